// Round 5
// baseline (178.468 us; speedup 1.0000x reference)
//
#include <hip/hip_runtime.h>
#include <math.h>

// B=2048, S=8, D=1280, K=1 rank-1 common-mode removal. 3-kernel pipeline:
//  K1 gram : block=batch (320 thr). float4 loads -> 44 partials -> 3-round
//            butterfly -> LDS combine -> 44 totals to ws. NO eigen here
//            (R4 lesson: serial eigen attached to streaming block serializes
//            blocks on the CU -> 50us; decouple it).
//  K2 eigen: wave=batch, 2048 waves all concurrent. 44 floats in, 8x8 top
//            eigenpair via shuffles, 17 coeffs + pc1/flag out. ~3us total.
//  K3 apply: pure streaming, coeffs via uniform scalar loads.

#define SV 8
#define DV 1280
#define D4 320             // float4 per row
#define BSTRIDE (SV*DV)    // 10240 floats per batch
#define LDW 44             // padded partial stride (floats); 40 used
#define NP 44              // gram totals per batch (36 cross + 8 sums)
#define WSS 17             // per-batch coeffs: a[8], coef[8], bconst

__global__ __launch_bounds__(320)
void cmr_gram(const float* __restrict__ feat,
              float* __restrict__ gram)
{
    __shared__ float lds[NP * LDW];       // 7744 B
    const int tid  = threadIdx.x;
    const int lane = tid & 63;
    const int wq   = tid >> 6;            // 0..4 = column chunk
    const int b    = blockIdx.x;

    // ---- load: 8 float4 per lane, fully coalesced ----
    const float4* __restrict__ f4 = (const float4*)(feat + (size_t)b * BSTRIDE);
    const int d4 = wq * 64 + lane;
    float4 f[8];
#pragma unroll
    for (int s = 0; s < 8; ++s) f[s] = f4[s * D4 + d4];

    // ---- 44 partials: 36 upper-tri cross products + 8 row sums ----
    float Sr[8], C[36];
#pragma unroll
    for (int s = 0; s < 8; ++s) Sr[s] = (f[s].x + f[s].y) + (f[s].z + f[s].w);
    {
        int idx = 0;
#pragma unroll
        for (int i2 = 0; i2 < 8; ++i2)
#pragma unroll
            for (int j2 = i2; j2 < 8; ++j2) {
                float t0 = fmaf(f[i2].x, f[j2].x, fmaf(f[i2].y, f[j2].y, 0.f));
                C[idx] = fmaf(f[i2].z, f[j2].z, fmaf(f[i2].w, f[j2].w, t0));
                ++idx;
            }
    }
    // 3-round butterfly -> lanes 0,8,..,56 hold 8-lane-group partial sums
#pragma unroll
    for (int m = 1; m <= 4; m <<= 1) {
#pragma unroll
        for (int s = 0; s < 8; ++s) Sr[s] += __shfl_xor(Sr[s], m);
#pragma unroll
        for (int t = 0; t < 36; ++t) C[t] += __shfl_xor(C[t], m);
    }
    {
        const int p = wq * 8 + (lane >> 3);   // 0..39
        if ((lane & 7) == 0) {
#pragma unroll
            for (int t = 0; t < 36; ++t) lds[t * LDW + p] = C[t];
#pragma unroll
            for (int s = 0; s < 8; ++s) lds[(36 + s) * LDW + p] = Sr[s];
        }
    }
    __syncthreads();
    if (wq != 0) return;

    // ---- wave 0: lane L sums the 40 partials of value L, stores to ws ----
    if (lane < NP) {
        const float4* l4 = (const float4*)lds;
        float4 a4 = make_float4(0.f, 0.f, 0.f, 0.f);
#pragma unroll
        for (int q = 0; q < 10; ++q) {
            float4 v = l4[lane * (LDW / 4) + q];
            a4.x += v.x; a4.y += v.y; a4.z += v.z; a4.w += v.w;
        }
        gram[(size_t)b * NP + lane] = (a4.x + a4.y) + (a4.z + a4.w);
    }
}

__global__ __launch_bounds__(256)
void cmr_eigen(const float* __restrict__ gram,
               const float* __restrict__ kp,
               const float* __restrict__ cmr_gate,
               float* __restrict__ coef,
               float* __restrict__ out,
               int Bn)
{
    const int lane = threadIdx.x & 63;
    const int b = blockIdx.x * 4 + (threadIdx.x >> 6);   // 1 wave = 1 batch

    // lane L holds gram total L (L<44); all 2048 chains run concurrently
    const int Lr = (lane < NP) ? lane : 0;
    const float tot = gram[(size_t)b * NP + Lr];

    // ---- lane (i,j) builds normalized Gram entry via gather shuffles ----
    const int i = lane >> 3, j = lane & 7;
    const int a_ = (i < j) ? i : j;
    const int b_ = (i < j) ? j : i;
    const int tii = 8 * i - (i * (i - 1)) / 2;
    const int tjj = 8 * j - (j * (j - 1)) / 2;
    const int tij = 8 * a_ - (a_ * (a_ - 1)) / 2 + (b_ - a_);
    const float Cij = __shfl(tot, tij);
    const float Ci  = __shfl(tot, tii);
    const float Cj  = __shfl(tot, tjj);
    const float Si  = __shfl(tot, 36 + i);
    const float Sj  = __shfl(tot, 36 + j);

    const float invD = 1.f / (float)DV;
    const float mui = Si * invD, muj = Sj * invD;
    const float vari = fmaxf(Ci * invD - mui * mui, 0.f);
    const float varj = fmaxf(Cj * invD - muj * muj, 0.f);
    const float sigi  = sqrtf(vari) + 1e-8f;       // numpy std(ddof=0)+1e-8
    const float rsigi = 1.f / sigi;
    const float rsigj = 1.f / (sqrtf(varj) + 1e-8f);
    const float G = ((Cij - (float)DV * mui * muj) * rsigi) * rsigj;

    // trace via 8-gather (diag lives on lanes 9k)
    float tr = 0.f;
#pragma unroll
    for (int k = 0; k < 8; ++k) tr += __shfl(G, 9 * k);

    // ---- 14x trace-normalized squaring (|A_ij| <= trace: overflow-proof) ----
    float A = G / fmaxf(tr, 1e-30f);
#pragma unroll
    for (int t = 0; t < 14; ++t) {
        float nb = 0.f;
#pragma unroll
        for (int k = 0; k < 8; ++k)
            nb = fmaf(__shfl(A, i * 8 + k), __shfl(A, k * 8 + j), nb);
        float dg = 0.f;
#pragma unroll
        for (int k = 0; k < 8; ++k) dg += __shfl(nb, 9 * k);
        A = nb / fmaxf(dg, 1e-30f);
    }
    // argmax over diagonal (uniform across lanes) -> dominant column ~ u1
    float best = __shfl(A, 0); int bj = 0;
#pragma unroll
    for (int k = 1; k < 8; ++k) {
        float dk = __shfl(A, 9 * k);
        if (dk > best) { best = dk; bj = k; }
    }
    float u = __shfl(A, i * 8 + bj);               // u_i on all lanes of row i
    {
        float nn = 0.f;
#pragma unroll
        for (int k = 0; k < 8; ++k) nn += __shfl(u * u, 9 * k);
        u *= rsqrtf(fmaxf(nn, 1e-30f));
    }
    // 2 power-iteration polish steps on G
#pragma unroll
    for (int it = 0; it < 2; ++it) {
        float y = G * __shfl(u, 9 * j);            // G[i][j] * u_j
#pragma unroll
        for (int m = 1; m <= 4; m <<= 1) y += __shfl_xor(y, m);  // row sum -> y_i
        float ny = 0.f;
#pragma unroll
        for (int k = 0; k < 8; ++k) ny += __shfl(y * y, 9 * k);
        u = y * rsqrtf(fmaxf(ny, 1e-30f));
    }
    // Rayleigh quotient lambda1 = u^T G u
    float v = G * u * __shfl(u, 9 * j);
#pragma unroll
    for (int m = 1; m <= 4; m <<= 1) v += __shfl_xor(v, m);
    float lam = 0.f;
#pragma unroll
    for (int k = 0; k < 8; ++k) lam += __shfl(v, 9 * k);
    const float pc1 = lam / (tr + 1e-8f);

    // gates
    const float gate = 1.f / (1.f + expf(-cmr_gate[0]));
    const float kpg  = (kp[b] >= 5.0f) ? 1.5f : 1.0f;
    const float Gt   = gate * kpg;

    // bconst = sum_s u_s * rsig_s * mu_s (gather from diag lanes)
    float bc = 0.f;
#pragma unroll
    for (int k = 0; k < 8; ++k) bc += __shfl(u * rsigi * mui, 9 * k);

    float* wsb = coef + (size_t)b * WSS;
    if (j == 0) {
        wsb[i]     = u * rsigi;        // a_i   : p = sum a_s f[s,d] - bc
        wsb[8 + i] = Gt * sigi * u;    // coef_i: out = f - coef_s * p
    }
    if (lane == 0) {
        wsb[16] = bc;
        out[(size_t)Bn * BSTRIDE + b] = pc1;
        const float flag = (pc1 >= 0.6f ? 1.f : 0.f) + (pc1 >= 0.8f ? 1.f : 0.f);
        out[(size_t)Bn * BSTRIDE + Bn + b] = flag;
    }
}

__global__ __launch_bounds__(320)
void cmr_apply(const float* __restrict__ feat,
               const float* __restrict__ coef,
               float* __restrict__ out)
{
    const int tid  = threadIdx.x;
    const int lane = tid & 63;
    const int wq   = tid >> 6;
    const int b    = blockIdx.x;

    // uniform address per block -> scalar loads
    const float* __restrict__ wsb = coef + (size_t)b * WSS;
    float a[8], c[8];
#pragma unroll
    for (int s = 0; s < 8; ++s) { a[s] = wsb[s]; c[s] = wsb[8 + s]; }
    const float bc = wsb[16];

    const float4* __restrict__ f4 = (const float4*)(feat + (size_t)b * BSTRIDE);
    float4* __restrict__ o4 = (float4*)(out + (size_t)b * BSTRIDE);
    const int d4 = wq * 64 + lane;

    float4 f[8];
#pragma unroll
    for (int s = 0; s < 8; ++s) f[s] = f4[s * D4 + d4];

    float4 p = make_float4(-bc, -bc, -bc, -bc);
#pragma unroll
    for (int s = 0; s < 8; ++s) {
        p.x = fmaf(a[s], f[s].x, p.x);
        p.y = fmaf(a[s], f[s].y, p.y);
        p.z = fmaf(a[s], f[s].z, p.z);
        p.w = fmaf(a[s], f[s].w, p.w);
    }
#pragma unroll
    for (int s = 0; s < 8; ++s) {
        float4 o;
        o.x = fmaf(-c[s], p.x, f[s].x);
        o.y = fmaf(-c[s], p.y, f[s].y);
        o.z = fmaf(-c[s], p.z, f[s].z);
        o.w = fmaf(-c[s], p.w, f[s].w);
        o4[s * D4 + d4] = o;
    }
}

extern "C" void kernel_launch(void* const* d_in, const int* in_sizes, int n_in,
                              void* d_out, int out_size, void* d_ws, size_t ws_size,
                              hipStream_t stream) {
    const float* feat = (const float*)d_in[0];
    const float* kp   = (const float*)d_in[1];
    const float* gate = (const float*)d_in[2];
    float* out = (float*)d_out;
    const int Bn = in_sizes[0] / BSTRIDE;       // 2048

    float* gram = (float*)d_ws;                  // Bn*44 floats
    float* coef = gram + (size_t)Bn * NP;        // Bn*17 floats

    cmr_gram <<<Bn,      320, 0, stream>>>(feat, gram);
    cmr_eigen<<<Bn / 4,  256, 0, stream>>>(gram, kp, gate, coef, out, Bn);
    cmr_apply<<<Bn,      320, 0, stream>>>(feat, coef, out);
}

// Round 7
// 174.492 us; speedup vs baseline: 1.0228x; 1.0228x over previous
//
#include <hip/hip_runtime.h>
#include <math.h>

// B=2048, S=8, D=1280, K=1 rank-1 common-mode removal.
// R7: MFMA gram with fp32-accurate hi/lo bf16 split (R6 failed on bf16
// input rounding: absmax 0.117 vs 0.105). G = HH + HL + HL^T where
// f = hi + lo, HH = hi*hi^T, HL = hi*lo^T; lo*lo^T ~ 2^-18 rel, dropped.
// Zero cross-lane / LDS ops anywhere (R2/R4/R5 plateaued ~50us on DS pipe).
//  K1 gram : 1 wave per 2 batches (16x16 MFMA tile), 4 MFMAs per 32-col chunk.
//  K2 eigen: 1 THREAD per batch, 8x8 in registers, constant-indexed arrays.
//  K3 apply: pure streaming.

#define SV 8
#define DV 1280
#define D4 320             // float4 per row
#define BSTRIDE (SV*DV)    // 10240 floats per batch
#define GSZ 136            // per-batch ws: HH[64] + HL[64] + S[8]
#define WSS 17             // per-batch coeffs: a[8], coef[8], bconst

typedef __attribute__((ext_vector_type(8))) short bf16x8;
typedef __attribute__((ext_vector_type(4))) float f32x4;

union BF8 { bf16x8 v; short s[8]; };

__device__ __forceinline__ short f2bf(float x) {   // RNE, finite inputs
    unsigned u = __float_as_uint(x);
    return (short)((u + 0x7FFFu + ((u >> 16) & 1u)) >> 16);
}
__device__ __forceinline__ float bf2f(short h) {
    return __uint_as_float(((unsigned)(unsigned short)h) << 16);
}

__global__ __launch_bounds__(256)
void cmr_gram(const float* __restrict__ feat, float* __restrict__ gram)
{
    const int lane = threadIdx.x & 63;
    const int wid  = (blockIdx.x * 256 + threadIdx.x) >> 6;  // wave = batch PAIR
    const int m    = lane & 15;        // tile row/col: 0-7 batch0, 8-15 batch1
    const int quad = lane >> 4;        // k sub-offset = quad*8
    const int bt   = m >> 3;
    const int row  = m & 7;

    const float* __restrict__ fb =
        feat + ((size_t)(wid * 2 + bt)) * BSTRIDE + (size_t)row * DV;

    BF8 ones;
#pragma unroll
    for (int j = 0; j < 8; ++j) ones.s[j] = (short)0x3F80;   // bf16 1.0

    f32x4 accHH = {0.f, 0.f, 0.f, 0.f};
    f32x4 accHL = {0.f, 0.f, 0.f, 0.f};
    f32x4 accS  = {0.f, 0.f, 0.f, 0.f};

#pragma unroll 4
    for (int c = 0; c < 40; ++c) {
        const int k0 = c * 32 + quad * 8;
        const float4 x0 = *(const float4*)(fb + k0);
        const float4 x1 = *(const float4*)(fb + k0 + 4);
        float x[8] = {x0.x, x0.y, x0.z, x0.w, x1.x, x1.y, x1.z, x1.w};
        BF8 hi, lo;
#pragma unroll
        for (int j = 0; j < 8; ++j) {
            hi.s[j] = f2bf(x[j]);
            lo.s[j] = f2bf(x[j] - bf2f(hi.s[j]));
        }
        // HH[m][n] += sum_k hi[m]k hi[n]k ; HL[m][n] += sum_k hi[m]k lo[n]k
        accHH = __builtin_amdgcn_mfma_f32_16x16x32_bf16(hi.v, hi.v,   accHH, 0, 0, 0);
        accHL = __builtin_amdgcn_mfma_f32_16x16x32_bf16(hi.v, lo.v,   accHL, 0, 0, 0);
        // row sums: S[m] = sum_k (hi+lo)[m]k  (every column identical)
        accS  = __builtin_amdgcn_mfma_f32_16x16x32_bf16(hi.v, ones.v, accS,  0, 0, 0);
        accS  = __builtin_amdgcn_mfma_f32_16x16x32_bf16(lo.v, ones.v, accS,  0, 0, 0);
    }

    // C/D layout: lane l, reg r -> row=(l>>4)*4+r, col=l&15  [m89/m91]
    const int colb = (lane & 15) >> 3;
    const int col  = lane & 7;
#pragma unroll
    for (int r = 0; r < 4; ++r) {
        const int rowg = quad * 4 + r;            // 0..15
        if ((rowg >> 3) == colb) {                // same-batch diagonal blocks
            float* gb = gram + ((size_t)(wid * 2 + colb)) * GSZ;
            gb[(rowg & 7) * 8 + col]      = accHH[r];
            gb[64 + (rowg & 7) * 8 + col] = accHL[r];
        }
    }
    if ((lane & 15) == 0) {                       // col-0 lanes: 0,16,32,48
#pragma unroll
        for (int r = 0; r < 4; ++r) {
            const int rowg = quad * 4 + r;
            gram[((size_t)(wid * 2 + (rowg >> 3))) * GSZ + 128 + (rowg & 7)] = accS[r];
        }
    }
}

__global__ __launch_bounds__(64, 1)
void cmr_eigen(const float* __restrict__ gram,
               const float* __restrict__ kp,
               const float* __restrict__ cmr_gate,
               float* __restrict__ coef,
               float* __restrict__ out,
               int Bn)
{
    const int b = blockIdx.x * 64 + threadIdx.x;   // 1 thread = 1 batch
    const float* __restrict__ g = gram + (size_t)b * GSZ;

    float G[8][8], S[8], mu[8], sig[8], rsig[8];
#pragma unroll
    for (int i = 0; i < 8; ++i) {
#pragma unroll
        for (int j = 0; j < 8; ++j)
            G[i][j] = g[i * 8 + j] + g[64 + i * 8 + j] + g[64 + j * 8 + i];
        S[i] = g[128 + i];
    }
    const float invD = 1.f / (float)DV;
#pragma unroll
    for (int i = 0; i < 8; ++i) {
        mu[i] = S[i] * invD;
        const float var = fmaxf(G[i][i] * invD - mu[i] * mu[i], 0.f);
        sig[i]  = sqrtf(var) + 1e-8f;              // numpy std(ddof=0)+1e-8
        rsig[i] = 1.f / sig[i];
    }
    // normalize in place: G <- Gram of standardized rows
#pragma unroll
    for (int i = 0; i < 8; ++i)
#pragma unroll
        for (int j = 0; j < 8; ++j)
            G[i][j] = (G[i][j] - (float)DV * mu[i] * mu[j]) * rsig[i] * rsig[j];

    float tr = 0.f;
#pragma unroll
    for (int i = 0; i < 8; ++i) tr += G[i][i];

    // ---- 12x symmetric trace-normalized squaring (constant-indexed regs) ----
    float A[8][8];
    {
        const float rt = 1.f / fmaxf(tr, 1e-30f);
#pragma unroll
        for (int i = 0; i < 8; ++i)
#pragma unroll
            for (int j = 0; j < 8; ++j) A[i][j] = G[i][j] * rt;
    }
#pragma unroll
    for (int t = 0; t < 12; ++t) {
        float Bm[8][8];
        float trB = 0.f;
#pragma unroll
        for (int i = 0; i < 8; ++i)
#pragma unroll
            for (int j = i; j < 8; ++j) {
                float acc = 0.f;
#pragma unroll
                for (int k = 0; k < 8; ++k)
                    acc = fmaf(A[i][k], A[j][k], acc);   // A symmetric
                Bm[i][j] = acc;
                if (i == j) trB += acc;
            }
        const float rt = 1.f / fmaxf(trB, 1e-30f);
#pragma unroll
        for (int i = 0; i < 8; ++i)
#pragma unroll
            for (int j = i; j < 8; ++j) {
                const float v = Bm[i][j] * rt;
                A[i][j] = v; A[j][i] = v;
            }
    }
    // diag argmax -> dominant column ~ u1 (A ~= u u^T)
    int bj = 0; float best = A[0][0];
#pragma unroll
    for (int k = 1; k < 8; ++k)
        if (A[k][k] > best) { best = A[k][k]; bj = k; }
    float u[8];
#pragma unroll
    for (int i = 0; i < 8; ++i) {
        float v = A[i][0];
#pragma unroll
        for (int k = 1; k < 8; ++k) v = (bj == k) ? A[i][k] : v;
        u[i] = v;
    }
    {
        float nn = 0.f;
#pragma unroll
        for (int i = 0; i < 8; ++i) nn = fmaf(u[i], u[i], nn);
        const float r = rsqrtf(fmaxf(nn, 1e-30f));
#pragma unroll
        for (int i = 0; i < 8; ++i) u[i] *= r;
    }
    // 2 power-iteration polish steps on G
#pragma unroll
    for (int it = 0; it < 2; ++it) {
        float y[8]; float ny = 0.f;
#pragma unroll
        for (int i = 0; i < 8; ++i) {
            float acc = 0.f;
#pragma unroll
            for (int k = 0; k < 8; ++k) acc = fmaf(G[i][k], u[k], acc);
            y[i] = acc; ny = fmaf(acc, acc, ny);
        }
        const float r = rsqrtf(fmaxf(ny, 1e-30f));
#pragma unroll
        for (int i = 0; i < 8; ++i) u[i] = y[i] * r;
    }
    // Rayleigh quotient
    float lam = 0.f;
#pragma unroll
    for (int i = 0; i < 8; ++i) {
        float acc = 0.f;
#pragma unroll
        for (int k = 0; k < 8; ++k) acc = fmaf(G[i][k], u[k], acc);
        lam = fmaf(u[i], acc, lam);
    }
    const float pc1 = lam / (tr + 1e-8f);

    const float gate = 1.f / (1.f + expf(-cmr_gate[0]));
    const float kpg  = (kp[b] >= 5.0f) ? 1.5f : 1.0f;
    const float Gt   = gate * kpg;

    float bc = 0.f;
#pragma unroll
    for (int i = 0; i < 8; ++i) bc = fmaf(u[i] * rsig[i], mu[i], bc);

    float* wsb = coef + (size_t)b * WSS;
#pragma unroll
    for (int i = 0; i < 8; ++i) {
        wsb[i]     = u[i] * rsig[i];     // a_i   : p = sum a_s f[s,d] - bc
        wsb[8 + i] = Gt * sig[i] * u[i]; // coef_i: out = f - coef_s * p
    }
    wsb[16] = bc;
    out[(size_t)Bn * BSTRIDE + b] = pc1;
    out[(size_t)Bn * BSTRIDE + Bn + b] =
        (pc1 >= 0.6f ? 1.f : 0.f) + (pc1 >= 0.8f ? 1.f : 0.f);
}

__global__ __launch_bounds__(320)
void cmr_apply(const float* __restrict__ feat,
               const float* __restrict__ coef,
               float* __restrict__ out)
{
    const int tid  = threadIdx.x;
    const int lane = tid & 63;
    const int wq   = tid >> 6;
    const int b    = blockIdx.x;

    const float* __restrict__ wsb = coef + (size_t)b * WSS;  // uniform -> s-loads
    float a[8], c[8];
#pragma unroll
    for (int s = 0; s < 8; ++s) { a[s] = wsb[s]; c[s] = wsb[8 + s]; }
    const float bc = wsb[16];

    const float4* __restrict__ f4 = (const float4*)(feat + (size_t)b * BSTRIDE);
    float4* __restrict__ o4 = (float4*)(out + (size_t)b * BSTRIDE);
    const int d4 = wq * 64 + lane;

    float4 f[8];
#pragma unroll
    for (int s = 0; s < 8; ++s) f[s] = f4[s * D4 + d4];

    float4 p = make_float4(-bc, -bc, -bc, -bc);
#pragma unroll
    for (int s = 0; s < 8; ++s) {
        p.x = fmaf(a[s], f[s].x, p.x);
        p.y = fmaf(a[s], f[s].y, p.y);
        p.z = fmaf(a[s], f[s].z, p.z);
        p.w = fmaf(a[s], f[s].w, p.w);
    }
#pragma unroll
    for (int s = 0; s < 8; ++s) {
        float4 o;
        o.x = fmaf(-c[s], p.x, f[s].x);
        o.y = fmaf(-c[s], p.y, f[s].y);
        o.z = fmaf(-c[s], p.z, f[s].z);
        o.w = fmaf(-c[s], p.w, f[s].w);
        o4[s * D4 + d4] = o;
    }
}

extern "C" void kernel_launch(void* const* d_in, const int* in_sizes, int n_in,
                              void* d_out, int out_size, void* d_ws, size_t ws_size,
                              hipStream_t stream) {
    const float* feat = (const float*)d_in[0];
    const float* kp   = (const float*)d_in[1];
    const float* gate = (const float*)d_in[2];
    float* out = (float*)d_out;
    const int Bn = in_sizes[0] / BSTRIDE;        // 2048

    float* gram = (float*)d_ws;                  // Bn*136 floats
    float* coef = gram + (size_t)Bn * GSZ;       // Bn*17 floats

    cmr_gram <<<Bn / 8,  256, 0, stream>>>(feat, gram);          // 1 wave = 2 batches
    cmr_eigen<<<Bn / 64, 64,  0, stream>>>(gram, kp, gate, coef, out, Bn);
    cmr_apply<<<Bn,      320, 0, stream>>>(feat, coef, out);
}